// Round 1
// baseline (491.471 us; speedup 1.0000x reference)
//
#include <hip/hip_runtime.h>

#define B_ROWS 8192
#define WIDTH  512
#define DEPTH  7
#define CIN    4096
#define EPS    1e-5f
#define SLOPE  0.01f

typedef __attribute__((ext_vector_type(8))) short short8;
typedef __attribute__((ext_vector_type(4))) short short4v;
typedef __attribute__((ext_vector_type(4))) float f32x4;

// round-to-nearest-even f32 -> bf16 bits
__device__ inline short f2bf(float f) {
  unsigned u = __builtin_bit_cast(unsigned, f);
  unsigned r = (u + 0x7FFFu + ((u >> 16) & 1u)) >> 16;
  return (short)r;
}

__device__ inline void gl_lds16(const void* g, void* l) {
  __builtin_amdgcn_global_load_lds(
      (const __attribute__((address_space(1))) unsigned*)g,
      (__attribute__((address_space(3))) unsigned*)l, 16, 0, 0);
}

// ---------------- weight conversion: 7 fp32 W's -> packed bf16 ----------------
struct WP { const float* p[7]; };

__global__ __launch_bounds__(256) void convw(WP wp, short* __restrict__ out) {
  long e = ((long)blockIdx.x * 256 + threadIdx.x) * 4;  // 4 elems/thread
  // cumulative boundaries: 262144 * tri(i)
  int layer; long base;
  if      (e < 262144L)  { layer = 0; base = 0; }
  else if (e < 786432L)  { layer = 1; base = 262144L; }
  else if (e < 1572864L) { layer = 2; base = 786432L; }
  else if (e < 2621440L) { layer = 3; base = 1572864L; }
  else if (e < 3932160L) { layer = 4; base = 2621440L; }
  else if (e < 5505024L) { layer = 5; base = 3932160L; }
  else                   { layer = 6; base = 5505024L; }
  f32x4 v = *(const f32x4*)(wp.p[layer] + (e - base));
  short4v o;
  o.x = f2bf(v.x); o.y = f2bf(v.y); o.z = f2bf(v.z); o.w = f2bf(v.w);
  *(short4v*)(out + e) = o;
}

// ---------------- x -> bf16 concat buffer + classifier partial ----------------
__global__ __launch_bounds__(256) void initx(const float* __restrict__ x,
                                             const float* __restrict__ wc,
                                             short* __restrict__ lastbf,
                                             float* __restrict__ logit) {
  int w = threadIdx.x >> 6, l = threadIdx.x & 63;
  int r = blockIdx.x * 4 + w;
  const float* xr = x + (long)r * 512 + l * 8;
  f32x4 v0 = *(const f32x4*)xr;
  f32x4 v1 = *(const f32x4*)(xr + 4);
  const float* wcr = wc + l * 8;
  float acc = 0.f;
  short8 ob;
#pragma unroll
  for (int j = 0; j < 4; ++j) { acc += v0[j] * wcr[j];     ob[j]     = f2bf(v0[j]); }
#pragma unroll
  for (int j = 0; j < 4; ++j) { acc += v1[j] * wcr[4 + j]; ob[4 + j] = f2bf(v1[j]); }
  *(short8*)&lastbf[(long)r * CIN + l * 8] = ob;
#pragma unroll
  for (int off = 32; off; off >>= 1) acc += __shfl_xor(acc, off);
  if (l == 0) logit[r] = acc;
}

// ---------------- bf16 MFMA GEMM: hpre[b][w] = sum_k last[b][k] * W[w][k] -----
#define BM 128
#define BN 128
#define BK 32

__global__ __launch_bounds__(256) void gemm_bt(const short* __restrict__ A,
                                               const short* __restrict__ Bw,
                                               float* __restrict__ C, int K) {
  __shared__ short As[BM * BK];
  __shared__ short Bs[BN * BK];
  int t = threadIdx.x;
  int w = t >> 6, l = t & 63;
  int bm = blockIdx.x, bn = blockIdx.y;
  int wm = w >> 1, wn = w & 1;  // 2x2 waves, each owns 64x64 of the 128x128 tile
  f32x4 acc[4][4];
#pragma unroll
  for (int m = 0; m < 4; ++m)
#pragma unroll
    for (int n = 0; n < 4; ++n) acc[m][n] = f32x4{0.f, 0.f, 0.f, 0.f};

  const short* Ab = A + (long)(bm * BM) * CIN;
  const short* Bb = Bw + (long)(bn * BN) * K;
  int row_st = t >> 2;          // 0..63
  int kc = (t & 3) * 8;         // 0,8,16,24
  char* AsB = (char*)As;
  char* BsB = (char*)Bs;
  int wb = w * 1024;            // wave-uniform LDS byte base (lane*16 added by HW)

  for (int k0 = 0; k0 < K; k0 += BK) {
    gl_lds16(Ab + (long)row_st * CIN + k0 + kc,        AsB + wb);
    gl_lds16(Ab + (long)(row_st + 64) * CIN + k0 + kc, AsB + 4096 + wb);
    gl_lds16(Bb + (long)row_st * K + k0 + kc,          BsB + wb);
    gl_lds16(Bb + (long)(row_st + 64) * K + k0 + kc,   BsB + 4096 + wb);
    __syncthreads();  // compiler drains vmcnt before s_barrier

    int lk = (l >> 4) * 8;
    int lr = l & 15;
    short8 a[4], b[4];
#pragma unroll
    for (int m = 0; m < 4; ++m)
      a[m] = *(const short8*)&As[(wm * 64 + m * 16 + lr) * BK + lk];
#pragma unroll
    for (int n = 0; n < 4; ++n)
      b[n] = *(const short8*)&Bs[(wn * 64 + n * 16 + lr) * BK + lk];
#pragma unroll
    for (int m = 0; m < 4; ++m)
#pragma unroll
      for (int n = 0; n < 4; ++n)
        acc[m][n] = __builtin_amdgcn_mfma_f32_16x16x32_bf16(a[m], b[n], acc[m][n], 0, 0, 0);
    __syncthreads();  // all reads done before next stage
  }

  int lr = l & 15, lg = l >> 4;
#pragma unroll
  for (int m = 0; m < 4; ++m) {
    int row = bm * BM + wm * 64 + m * 16 + lg * 4;
#pragma unroll
    for (int n = 0; n < 4; ++n) {
      int col = bn * BN + wn * 64 + n * 16 + lr;
#pragma unroll
      for (int j = 0; j < 4; ++j)
        C[(long)(row + j) * WIDTH + col] = acc[m][n][j];
    }
  }
}

// ---------------- per-column batch stats (sum, sumsq) -------------------------
__global__ __launch_bounds__(256) void colstats(const float* __restrict__ h,
                                                float* __restrict__ sums) {
  int t = threadIdx.x;
  int r0 = blockIdx.x * 128;
  float s0 = 0.f, q0 = 0.f, s1 = 0.f, q1 = 0.f;
  const int c0 = t, c1 = t + 256;
  for (int r = r0; r < r0 + 128; ++r) {
    float v0 = h[(long)r * WIDTH + c0];
    float v1 = h[(long)r * WIDTH + c1];
    s0 += v0; q0 += v0 * v0;
    s1 += v1; q1 += v1 * v1;
  }
  atomicAdd(&sums[c0], s0);
  atomicAdd(&sums[WIDTH + c0], q0);
  atomicAdd(&sums[c1], s1);
  atomicAdd(&sums[WIDTH + c1], q1);
}

// ---------------- BN + LeakyReLU + noise + classifier partial + bf16 store ----
__global__ __launch_bounds__(256) void bnact(const float* __restrict__ h,
                                             const float* __restrict__ sums,
                                             const float* __restrict__ gamma,
                                             const float* __restrict__ beta,
                                             const float* __restrict__ noise,
                                             const float* __restrict__ wc,
                                             short* __restrict__ lastseg,
                                             float* __restrict__ logit) {
  int w = threadIdx.x >> 6, l = threadIdx.x & 63;
  int r = blockIdx.x * 4 + w;
  int c = l * 8;
  const float invB = 1.0f / 8192.0f;
  f32x4 h0 = *(const f32x4*)&h[(long)r * WIDTH + c];
  f32x4 h1 = *(const f32x4*)&h[(long)r * WIDTH + c + 4];
  f32x4 n0 = *(const f32x4*)&noise[(long)r * WIDTH + c];
  f32x4 n1 = *(const f32x4*)&noise[(long)r * WIDTH + c + 4];
  float acc = 0.f;
  short8 ob;
#pragma unroll
  for (int j = 0; j < 8; ++j) {
    int cc = c + j;
    float hv = j < 4 ? h0[j] : h1[j - 4];
    float nv = j < 4 ? n0[j] : n1[j - 4];
    float mean = sums[cc] * invB;
    float var = sums[WIDTH + cc] * invB - mean * mean;
    float v = (hv - mean) * rsqrtf(var + EPS);
    v = v * gamma[cc] + beta[cc];
    v = v >= 0.f ? v : SLOPE * v;
    v *= nv;
    acc += v * wc[cc];
    ob[j] = f2bf(v);
  }
  *(short8*)&lastseg[(long)r * CIN + c] = ob;
#pragma unroll
  for (int off = 32; off; off >>= 1) acc += __shfl_xor(acc, off);
  if (l == 0) logit[r] += acc;  // one wave per row: no race
}

// ---------------- sigmoid ----------------------------------------------------
__global__ __launch_bounds__(256) void finalize(const float* __restrict__ logit,
                                                const float* __restrict__ bc,
                                                float* __restrict__ out) {
  int i = blockIdx.x * 256 + threadIdx.x;
  float z = logit[i] + bc[0];
  out[i] = 1.0f / (1.0f + expf(-z));
}

extern "C" void kernel_launch(void* const* d_in, const int* in_sizes, int n_in,
                              void* d_out, int out_size, void* d_ws, size_t ws_size,
                              hipStream_t stream) {
  (void)in_sizes; (void)n_in; (void)out_size; (void)ws_size;
  const float* x     = (const float*)d_in[0];
  WP wp;
  for (int i = 0; i < 7; ++i) wp.p[i] = (const float*)d_in[1 + i];
  // d_in[8] = b (linear bias) — cancels exactly through training-mode BN; unused.
  const float* gamma = (const float*)d_in[9];
  const float* beta  = (const float*)d_in[10];
  const float* Wc    = (const float*)d_in[11];
  const float* bc    = (const float*)d_in[12];
  const float* noise = (const float*)d_in[13];

  char* ws = (char*)d_ws;
  short* lastbf = (short*)ws;                               // 8192*4096 bf16 = 64 MiB
  float* hpre   = (float*)(ws + 67108864);                  // 8192*512 f32  = 16 MiB
  short* wbf    = (short*)(ws + 67108864 + 16777216);       // 7.34M bf16    = 14 MiB
  float* sums   = (float*)(ws + 67108864 + 16777216 + 14680064);   // 7*1024 f32
  float* logit  = (float*)(ws + 67108864 + 16777216 + 14680064 + 28672);  // 8192 f32

  hipMemsetAsync(sums, 0, DEPTH * 1024 * sizeof(float), stream);
  convw<<<7168, 256, 0, stream>>>(wp, wbf);
  initx<<<2048, 256, 0, stream>>>(x, Wc, lastbf, logit);

  long woff = 0;
  for (int i = 0; i < DEPTH; ++i) {
    int K = 512 * (i + 1);
    gemm_bt<<<dim3(64, 4), 256, 0, stream>>>(lastbf, wbf + woff, hpre, K);
    colstats<<<64, 256, 0, stream>>>(hpre, sums + i * 1024);
    bnact<<<2048, 256, 0, stream>>>(hpre, sums + i * 1024,
                                    gamma + i * 512, beta + i * 512,
                                    noise + (long)i * B_ROWS * WIDTH,
                                    Wc + 512 + i * 512,
                                    lastbf + 512 + (long)i * 512, logit);
    woff += (long)512 * K;
  }
  finalize<<<32, 256, 0, stream>>>(logit, bc, (float*)d_out);
}

// Round 2
// 320.052 us; speedup vs baseline: 1.5356x; 1.5356x over previous
//
#include <hip/hip_runtime.h>

#define B_ROWS 8192
#define WIDTH  512
#define DEPTH  7
#define CIN    4096
#define EPS    1e-5f
#define SLOPE  0.01f

typedef __attribute__((ext_vector_type(8))) short short8;
typedef __attribute__((ext_vector_type(4))) short short4v;
typedef __attribute__((ext_vector_type(4))) float f32x4;

// round-to-nearest-even f32 -> bf16 bits
__device__ inline short f2bf(float f) {
  unsigned u = __builtin_bit_cast(unsigned, f);
  unsigned r = (u + 0x7FFFu + ((u >> 16) & 1u)) >> 16;
  return (short)r;
}

__device__ inline void gl_lds16(const void* g, void* l) {
  __builtin_amdgcn_global_load_lds(
      (const __attribute__((address_space(1))) unsigned*)g,
      (__attribute__((address_space(3))) unsigned*)l, 16, 0, 0);
}

// ---------------- weight conversion: 7 fp32 W's -> packed bf16 ----------------
struct WP { const float* p[7]; };

__global__ __launch_bounds__(256) void convw(WP wp, short* __restrict__ out) {
  long e = ((long)blockIdx.x * 256 + threadIdx.x) * 4;  // 4 elems/thread
  int layer; long base;
  if      (e < 262144L)  { layer = 0; base = 0; }
  else if (e < 786432L)  { layer = 1; base = 262144L; }
  else if (e < 1572864L) { layer = 2; base = 786432L; }
  else if (e < 2621440L) { layer = 3; base = 1572864L; }
  else if (e < 3932160L) { layer = 4; base = 2621440L; }
  else if (e < 5505024L) { layer = 5; base = 3932160L; }
  else                   { layer = 6; base = 5505024L; }
  f32x4 v = *(const f32x4*)(wp.p[layer] + (e - base));
  short4v o;
  o.x = f2bf(v.x); o.y = f2bf(v.y); o.z = f2bf(v.z); o.w = f2bf(v.w);
  *(short4v*)(out + e) = o;
}

// ---------------- x -> bf16 concat buffer + classifier partial ----------------
__global__ __launch_bounds__(256) void initx(const float* __restrict__ x,
                                             const float* __restrict__ wc,
                                             short* __restrict__ lastbf,
                                             float* __restrict__ logit) {
  int w = threadIdx.x >> 6, l = threadIdx.x & 63;
  int r = blockIdx.x * 4 + w;
  const float* xr = x + (long)r * 512 + l * 8;
  f32x4 v0 = *(const f32x4*)xr;
  f32x4 v1 = *(const f32x4*)(xr + 4);
  const float* wcr = wc + l * 8;
  float acc = 0.f;
  short8 ob;
#pragma unroll
  for (int j = 0; j < 4; ++j) { acc += v0[j] * wcr[j];     ob[j]     = f2bf(v0[j]); }
#pragma unroll
  for (int j = 0; j < 4; ++j) { acc += v1[j] * wcr[4 + j]; ob[4 + j] = f2bf(v1[j]); }
  *(short8*)&lastbf[(long)r * CIN + l * 8] = ob;
#pragma unroll
  for (int off = 32; off; off >>= 1) acc += __shfl_xor(acc, off);
  if (l == 0) logit[r] = acc;
}

// ---------------- bf16 MFMA GEMM + fused column stats -------------------------
// 128x128 block tile, BK=64, 512 threads = 8 waves:
//   wave = (ws, wm, wn): ws = K-half split, (wm,wn) = 64x64 quadrant.
// LDS double-buffered, XOR-swizzled (byte ^= ((row&7)<<4) within 128B rows).
// Epilogue: ws=1 partials -> LDS -> ws=0 combines, writes C, and atomically
// accumulates per-column sum / sumsq (replaces the colstats kernel).
#define TM 128
#define TN 128
#define TK 64

__global__ __launch_bounds__(512) void gemm_fused(const short* __restrict__ A,
                                                  const short* __restrict__ Bw,
                                                  float* __restrict__ C,
                                                  float* __restrict__ sums,
                                                  int K) {
  __shared__ short As[2][TM * TK];   // 2 x 16 KB
  __shared__ short Bs[2][TN * TK];   // 2 x 16 KB
  __shared__ float Red[4][64 * 64];  // 64 KB partial-combine buffer
  int t = threadIdx.x;
  int w = t >> 6, l = t & 63;
  int ws = w >> 2, wq = w & 3;
  int wm = wq >> 1, wn = wq & 1;
  int lr = l & 15, lk0 = (l >> 4) * 8;

  int bm = blockIdx.x, bn = blockIdx.y;
  const short* Ab = A + (long)(bm * TM) * CIN;
  const short* Bb = Bw + (long)(bn * TN) * K;

  f32x4 acc[4][4];
#pragma unroll
  for (int m = 0; m < 4; ++m)
#pragma unroll
    for (int n = 0; n < 4; ++n) acc[m][n] = f32x4{0.f, 0.f, 0.f, 0.f};

  // staging: dest linear d = s*8192 + w*1024 + l*16 (HW adds l*16).
  // row = d>>7 = s*64 + w*8 + (l>>3); swizzled source col = ((l&7)^(l>>3))*8.
  int srow = w * 8 + (l >> 3);
  int skc  = ((l & 7) ^ (l >> 3)) << 3;

#define STAGE(buf, k0)                                                        \
  {                                                                           \
    char* AsB = (char*)As[buf];                                               \
    char* BsB = (char*)Bs[buf];                                               \
    gl_lds16(Ab + (long)srow * CIN + (k0) + skc,        AsB + w * 1024);      \
    gl_lds16(Ab + (long)(srow + 64) * CIN + (k0) + skc, AsB + 8192 + w * 1024);\
    gl_lds16(Bb + (long)srow * K + (k0) + skc,          BsB + w * 1024);      \
    gl_lds16(Bb + (long)(srow + 64) * K + (k0) + skc,   BsB + 8192 + w * 1024);\
  }

  STAGE(0, 0);
  __syncthreads();

  int nt = K >> 6;  // K is a multiple of 64
  int cur = 0;
  for (int tix = 0; tix < nt; ++tix) {
    if (tix + 1 < nt) STAGE(cur ^ 1, (tix + 1) << 6);
    short8 a[4], b[4];
#pragma unroll
    for (int m = 0; m < 4; ++m) {
      int row = wm * 64 + m * 16 + lr;
      int lb = row * 128 + ((ws * 32 + lk0) << 1);
      a[m] = *(const short8*)((const char*)As[cur] + (lb ^ ((lr & 7) << 4)));
    }
#pragma unroll
    for (int n = 0; n < 4; ++n) {
      int row = wn * 64 + n * 16 + lr;
      int lb = row * 128 + ((ws * 32 + lk0) << 1);
      b[n] = *(const short8*)((const char*)Bs[cur] + (lb ^ ((lr & 7) << 4)));
    }
#pragma unroll
    for (int m = 0; m < 4; ++m)
#pragma unroll
      for (int n = 0; n < 4; ++n)
        acc[m][n] = __builtin_amdgcn_mfma_f32_16x16x32_bf16(a[m], b[n], acc[m][n], 0, 0, 0);
    __syncthreads();  // staged buf^1 complete (vmcnt drained) + reads of cur done
    cur ^= 1;
  }

  // ---- combine K-halves, write C, accumulate column stats ----
  int lg = l >> 4;
  if (ws == 1) {
#pragma unroll
    for (int m = 0; m < 4; ++m)
#pragma unroll
      for (int n = 0; n < 4; ++n)
#pragma unroll
        for (int j = 0; j < 4; ++j)
          Red[wq][(m * 16 + lg * 4 + j) * 64 + n * 16 + lr] = acc[m][n][j];
  }
  __syncthreads();
  if (ws == 0) {
    float* Cb = C + (long)(bm * TM + wm * 64) * WIDTH + bn * TN + wn * 64;
#pragma unroll
    for (int n = 0; n < 4; ++n) {
      float s = 0.f, q = 0.f;
#pragma unroll
      for (int m = 0; m < 4; ++m) {
#pragma unroll
        for (int j = 0; j < 4; ++j) {
          float v = acc[m][n][j] + Red[wq][(m * 16 + lg * 4 + j) * 64 + n * 16 + lr];
          Cb[(long)(m * 16 + lg * 4 + j) * WIDTH + n * 16 + lr] = v;
          s += v; q += v * v;
        }
      }
      s += __shfl_xor(s, 16); s += __shfl_xor(s, 32);
      q += __shfl_xor(q, 16); q += __shfl_xor(q, 32);
      if (l < 16) {
        int colg = bn * TN + wn * 64 + n * 16 + l;
        atomicAdd(&sums[colg], s);
        atomicAdd(&sums[WIDTH + colg], q);
      }
    }
  }
#undef STAGE
}

// ---------------- BN + LeakyReLU + noise + classifier partial + bf16 store ----
__global__ __launch_bounds__(256) void bnact(const float* __restrict__ h,
                                             const float* __restrict__ sums,
                                             const float* __restrict__ gamma,
                                             const float* __restrict__ beta,
                                             const float* __restrict__ noise,
                                             const float* __restrict__ wc,
                                             short* __restrict__ lastseg,
                                             float* __restrict__ logit) {
  int w = threadIdx.x >> 6, l = threadIdx.x & 63;
  int r = blockIdx.x * 4 + w;
  int c = l * 8;
  const float invB = 1.0f / 8192.0f;
  f32x4 h0 = *(const f32x4*)&h[(long)r * WIDTH + c];
  f32x4 h1 = *(const f32x4*)&h[(long)r * WIDTH + c + 4];
  f32x4 n0 = *(const f32x4*)&noise[(long)r * WIDTH + c];
  f32x4 n1 = *(const f32x4*)&noise[(long)r * WIDTH + c + 4];
  float acc = 0.f;
  short8 ob;
#pragma unroll
  for (int j = 0; j < 8; ++j) {
    int cc = c + j;
    float hv = j < 4 ? h0[j] : h1[j - 4];
    float nv = j < 4 ? n0[j] : n1[j - 4];
    float mean = sums[cc] * invB;
    float var = sums[WIDTH + cc] * invB - mean * mean;
    float v = (hv - mean) * rsqrtf(var + EPS);
    v = v * gamma[cc] + beta[cc];
    v = v >= 0.f ? v : SLOPE * v;
    v *= nv;
    acc += v * wc[cc];
    ob[j] = f2bf(v);
  }
  *(short8*)&lastseg[(long)r * CIN + c] = ob;
#pragma unroll
  for (int off = 32; off; off >>= 1) acc += __shfl_xor(acc, off);
  if (l == 0) logit[r] += acc;  // one wave per row: no race
}

// ---------------- sigmoid ----------------------------------------------------
__global__ __launch_bounds__(256) void finalize(const float* __restrict__ logit,
                                                const float* __restrict__ bc,
                                                float* __restrict__ out) {
  int i = blockIdx.x * 256 + threadIdx.x;
  float z = logit[i] + bc[0];
  out[i] = 1.0f / (1.0f + expf(-z));
}

extern "C" void kernel_launch(void* const* d_in, const int* in_sizes, int n_in,
                              void* d_out, int out_size, void* d_ws, size_t ws_size,
                              hipStream_t stream) {
  (void)in_sizes; (void)n_in; (void)out_size; (void)ws_size;
  const float* x     = (const float*)d_in[0];
  WP wp;
  for (int i = 0; i < 7; ++i) wp.p[i] = (const float*)d_in[1 + i];
  // d_in[8] = b (linear bias) — cancels exactly through training-mode BN; unused.
  const float* gamma = (const float*)d_in[9];
  const float* beta  = (const float*)d_in[10];
  const float* Wc    = (const float*)d_in[11];
  const float* bc    = (const float*)d_in[12];
  const float* noise = (const float*)d_in[13];

  char* ws = (char*)d_ws;
  short* lastbf = (short*)ws;                               // 8192*4096 bf16 = 64 MiB
  float* hpre   = (float*)(ws + 67108864);                  // 8192*512 f32  = 16 MiB
  short* wbf    = (short*)(ws + 67108864 + 16777216);       // 7.34M bf16    = 14 MiB
  float* sums   = (float*)(ws + 67108864 + 16777216 + 14680064);   // 7*1024 f32
  float* logit  = (float*)(ws + 67108864 + 16777216 + 14680064 + 28672);  // 8192 f32

  hipMemsetAsync(sums, 0, DEPTH * 1024 * sizeof(float), stream);
  convw<<<7168, 256, 0, stream>>>(wp, wbf);
  initx<<<2048, 256, 0, stream>>>(x, Wc, lastbf, logit);

  long woff = 0;
  for (int i = 0; i < DEPTH; ++i) {
    int K = 512 * (i + 1);
    gemm_fused<<<dim3(64, 4), 512, 0, stream>>>(lastbf, wbf + woff, hpre,
                                                sums + i * 1024, K);
    bnact<<<2048, 256, 0, stream>>>(hpre, sums + i * 1024,
                                    gamma + i * 512, beta + i * 512,
                                    noise + (long)i * B_ROWS * WIDTH,
                                    Wc + 512 + i * 512,
                                    lastbf + 512 + (long)i * 512, logit);
    woff += (long)512 * K;
  }
  finalize<<<32, 256, 0, stream>>>(logit, bc, (float*)d_out);
}

// Round 3
// 310.585 us; speedup vs baseline: 1.5824x; 1.0305x over previous
//
#include <hip/hip_runtime.h>

#define B_ROWS 8192
#define WIDTH  512
#define DEPTH  7
#define CIN    4096
#define EPS    1e-5f
#define SLOPE  0.01f

typedef __attribute__((ext_vector_type(8))) short short8;
typedef __attribute__((ext_vector_type(4))) short short4v;
typedef __attribute__((ext_vector_type(4))) float f32x4;

// round-to-nearest-even f32 -> bf16 bits
__device__ inline short f2bf(float f) {
  unsigned u = __builtin_bit_cast(unsigned, f);
  unsigned r = (u + 0x7FFFu + ((u >> 16) & 1u)) >> 16;
  return (short)r;
}

__device__ inline void gl_lds16(const void* g, void* l) {
  __builtin_amdgcn_global_load_lds(
      (const __attribute__((address_space(1))) unsigned*)g,
      (__attribute__((address_space(3))) unsigned*)l, 16, 0, 0);
}

// ---------------- weight conversion: 7 fp32 W's -> packed bf16 ----------------
struct WP { const float* p[7]; };

__global__ __launch_bounds__(256) void convw(WP wp, short* __restrict__ out) {
  long e = ((long)blockIdx.x * 256 + threadIdx.x) * 4;  // 4 elems/thread
  int layer; long base;
  if      (e < 262144L)  { layer = 0; base = 0; }
  else if (e < 786432L)  { layer = 1; base = 262144L; }
  else if (e < 1572864L) { layer = 2; base = 786432L; }
  else if (e < 2621440L) { layer = 3; base = 1572864L; }
  else if (e < 3932160L) { layer = 4; base = 2621440L; }
  else if (e < 5505024L) { layer = 5; base = 3932160L; }
  else                   { layer = 6; base = 5505024L; }
  f32x4 v = *(const f32x4*)(wp.p[layer] + (e - base));
  short4v o;
  o.x = f2bf(v.x); o.y = f2bf(v.y); o.z = f2bf(v.z); o.w = f2bf(v.w);
  *(short4v*)(out + e) = o;
}

// ---------------- x -> bf16 concat buffer + classifier partial ----------------
__global__ __launch_bounds__(256) void initx(const float* __restrict__ x,
                                             const float* __restrict__ wc,
                                             short* __restrict__ lastbf,
                                             float* __restrict__ logit) {
  int w = threadIdx.x >> 6, l = threadIdx.x & 63;
  int r = blockIdx.x * 4 + w;
  const float* xr = x + (long)r * 512 + l * 8;
  f32x4 v0 = *(const f32x4*)xr;
  f32x4 v1 = *(const f32x4*)(xr + 4);
  const float* wcr = wc + l * 8;
  float acc = 0.f;
  short8 ob;
#pragma unroll
  for (int j = 0; j < 4; ++j) { acc += v0[j] * wcr[j];     ob[j]     = f2bf(v0[j]); }
#pragma unroll
  for (int j = 0; j < 4; ++j) { acc += v1[j] * wcr[4 + j]; ob[4 + j] = f2bf(v1[j]); }
  *(short8*)&lastbf[(long)r * CIN + l * 8] = ob;
#pragma unroll
  for (int off = 32; off; off >>= 1) acc += __shfl_xor(acc, off);
  if (l == 0) logit[r] = acc;
}

// ---------------- bf16 MFMA GEMM + fused column stats -------------------------
// 64x128 block tile, BK=64, grid (128,4) = 512 blocks -> 2 blocks/CU,
// 512 threads = 8 waves: (ks = K-half, wm, wn) -> wave-tile 32x64.
// LDS: double-buffered As(8KB)+Bs(16KB) = 48KB; Red (K-combine, 32KB) aliases
// the staging space (only used after the K-loop's final barrier).
// Epilogue: ks=1 partials -> Red -> ks=0 combines, writes C, and atomically
// accumulates per-column sum / sumsq.
__global__ __launch_bounds__(512, 4) void gemm_fused(const short* __restrict__ A,
                                                     const short* __restrict__ Bw,
                                                     float* __restrict__ C,
                                                     float* __restrict__ sums,
                                                     int K) {
  __shared__ __align__(16) char smem[49152];  // 2 x (As 8KB + Bs 16KB)
  int t = threadIdx.x;
  int w = t >> 6, l = t & 63;
  int ks = w >> 2, wq = w & 3;
  int wm = wq >> 1, wn = wq & 1;
  int lr = l & 15;
  int lg = l >> 4;
  int kb = ks * 64 + lg * 16;  // byte offset of this lane's k-slice within a 128B row

  int bm = blockIdx.x, bn = blockIdx.y;
  const short* Ab = A + (long)(bm * 64) * CIN;
  const short* Bb = Bw + (long)(bn * 128) * K;

  f32x4 acc[2][4];
#pragma unroll
  for (int m = 0; m < 2; ++m)
#pragma unroll
    for (int n = 0; n < 4; ++n) acc[m][n] = f32x4{0.f, 0.f, 0.f, 0.f};

  // staging: per ktile 24KB (As 8KB rows 0..63, Bs 16KB rows 0..127).
  // wave w stages 3x1KB chunks; dest row = chunk*8 + (l>>3), dest col16 = l&7.
  // source col is pre-swizzled so that read-side byte^((row&7)<<4) matches.
  int l8 = l >> 3;
  int scol = ((l & 7) ^ l8) << 3;  // element offset of the 16B chunk

#define STAGE(buf, k0)                                                          \
  {                                                                             \
    char* base = smem + (buf) * 24576;                                          \
    gl_lds16(Ab + (long)(w * 8 + l8) * CIN + (k0) + scol,      base + w * 1024);\
    gl_lds16(Bb + (long)(w * 8 + l8) * K + (k0) + scol,        base + 8192 + w * 1024); \
    gl_lds16(Bb + (long)(64 + w * 8 + l8) * K + (k0) + scol,   base + 16384 + w * 1024);\
  }

  STAGE(0, 0);
  __syncthreads();

  int nt = K >> 6;  // K is a multiple of 64
  int cur = 0;
  for (int tix = 0; tix < nt; ++tix) {
    if (tix + 1 < nt) STAGE(cur ^ 1, (tix + 1) << 6);
    const char* AsC = smem + cur * 24576;
    const char* BsC = AsC + 8192;
    short8 a[2], b[4];
#pragma unroll
    for (int m = 0; m < 2; ++m) {
      int row = wm * 32 + m * 16 + lr;
      a[m] = *(const short8*)(AsC + ((row * 128 + kb) ^ ((lr & 7) << 4)));
    }
#pragma unroll
    for (int n = 0; n < 4; ++n) {
      int row = wn * 64 + n * 16 + lr;
      b[n] = *(const short8*)(BsC + ((row * 128 + kb) ^ ((lr & 7) << 4)));
    }
#pragma unroll
    for (int m = 0; m < 2; ++m)
#pragma unroll
      for (int n = 0; n < 4; ++n)
        acc[m][n] = __builtin_amdgcn_mfma_f32_16x16x32_bf16(a[m], b[n], acc[m][n], 0, 0, 0);
    __syncthreads();  // staged buf^1 complete (vmcnt drained) + reads of cur done
    cur ^= 1;
  }

  // ---- combine K-halves (Red aliases staging LDS), write C, column stats ----
  float* Red = (float*)smem;  // [4][32*64] f32 = 32KB
  if (ks == 1) {
#pragma unroll
    for (int m = 0; m < 2; ++m)
#pragma unroll
      for (int n = 0; n < 4; ++n)
#pragma unroll
        for (int j = 0; j < 4; ++j)
          Red[wq * 2048 + (m * 16 + lg * 4 + j) * 64 + n * 16 + lr] = acc[m][n][j];
  }
  __syncthreads();
  if (ks == 0) {
    float* Cb = C + (long)(bm * 64 + wm * 32) * WIDTH + bn * 128 + wn * 64;
#pragma unroll
    for (int n = 0; n < 4; ++n) {
      float s = 0.f, q = 0.f;
#pragma unroll
      for (int m = 0; m < 2; ++m) {
#pragma unroll
        for (int j = 0; j < 4; ++j) {
          float v = acc[m][n][j] + Red[wq * 2048 + (m * 16 + lg * 4 + j) * 64 + n * 16 + lr];
          Cb[(long)(m * 16 + lg * 4 + j) * WIDTH + n * 16 + lr] = v;
          s += v; q += v * v;
        }
      }
      s += __shfl_xor(s, 16); s += __shfl_xor(s, 32);
      q += __shfl_xor(q, 16); q += __shfl_xor(q, 32);
      if (l < 16) {
        int colg = bn * 128 + wn * 64 + n * 16 + l;
        atomicAdd(&sums[colg], s);
        atomicAdd(&sums[WIDTH + colg], q);
      }
    }
  }
#undef STAGE
}

// ---------------- BN + LeakyReLU + noise + classifier partial + bf16 store ----
__global__ __launch_bounds__(256) void bnact(const float* __restrict__ h,
                                             const float* __restrict__ sums,
                                             const float* __restrict__ gamma,
                                             const float* __restrict__ beta,
                                             const float* __restrict__ noise,
                                             const float* __restrict__ wc,
                                             short* __restrict__ lastseg,
                                             float* __restrict__ logit) {
  int w = threadIdx.x >> 6, l = threadIdx.x & 63;
  int r = blockIdx.x * 4 + w;
  int c = l * 8;
  const float invB = 1.0f / 8192.0f;
  f32x4 h0 = *(const f32x4*)&h[(long)r * WIDTH + c];
  f32x4 h1 = *(const f32x4*)&h[(long)r * WIDTH + c + 4];
  f32x4 n0 = *(const f32x4*)&noise[(long)r * WIDTH + c];
  f32x4 n1 = *(const f32x4*)&noise[(long)r * WIDTH + c + 4];
  float acc = 0.f;
  short8 ob;
#pragma unroll
  for (int j = 0; j < 8; ++j) {
    int cc = c + j;
    float hv = j < 4 ? h0[j] : h1[j - 4];
    float nv = j < 4 ? n0[j] : n1[j - 4];
    float mean = sums[cc] * invB;
    float var = sums[WIDTH + cc] * invB - mean * mean;
    float v = (hv - mean) * rsqrtf(var + EPS);
    v = v * gamma[cc] + beta[cc];
    v = v >= 0.f ? v : SLOPE * v;
    v *= nv;
    acc += v * wc[cc];
    ob[j] = f2bf(v);
  }
  *(short8*)&lastseg[(long)r * CIN + c] = ob;
#pragma unroll
  for (int off = 32; off; off >>= 1) acc += __shfl_xor(acc, off);
  if (l == 0) logit[r] += acc;  // one wave per row: no race
}

// ---------------- sigmoid ----------------------------------------------------
__global__ __launch_bounds__(256) void finalize(const float* __restrict__ logit,
                                                const float* __restrict__ bc,
                                                float* __restrict__ out) {
  int i = blockIdx.x * 256 + threadIdx.x;
  float z = logit[i] + bc[0];
  out[i] = 1.0f / (1.0f + expf(-z));
}

extern "C" void kernel_launch(void* const* d_in, const int* in_sizes, int n_in,
                              void* d_out, int out_size, void* d_ws, size_t ws_size,
                              hipStream_t stream) {
  (void)in_sizes; (void)n_in; (void)out_size; (void)ws_size;
  const float* x     = (const float*)d_in[0];
  WP wp;
  for (int i = 0; i < 7; ++i) wp.p[i] = (const float*)d_in[1 + i];
  // d_in[8] = b (linear bias) — cancels exactly through training-mode BN; unused.
  const float* gamma = (const float*)d_in[9];
  const float* beta  = (const float*)d_in[10];
  const float* Wc    = (const float*)d_in[11];
  const float* bc    = (const float*)d_in[12];
  const float* noise = (const float*)d_in[13];

  char* ws = (char*)d_ws;
  short* lastbf = (short*)ws;                               // 8192*4096 bf16 = 64 MiB
  float* hpre   = (float*)(ws + 67108864);                  // 8192*512 f32  = 16 MiB
  short* wbf    = (short*)(ws + 67108864 + 16777216);       // 7.34M bf16    = 14 MiB
  float* sums   = (float*)(ws + 67108864 + 16777216 + 14680064);   // 7*1024 f32
  float* logit  = (float*)(ws + 67108864 + 16777216 + 14680064 + 28672);  // 8192 f32

  hipMemsetAsync(sums, 0, DEPTH * 1024 * sizeof(float), stream);
  convw<<<7168, 256, 0, stream>>>(wp, wbf);
  initx<<<2048, 256, 0, stream>>>(x, Wc, lastbf, logit);

  long woff = 0;
  for (int i = 0; i < DEPTH; ++i) {
    int K = 512 * (i + 1);
    gemm_fused<<<dim3(128, 4), 512, 0, stream>>>(lastbf, wbf + woff, hpre,
                                                 sums + i * 1024, K);
    bnact<<<2048, 256, 0, stream>>>(hpre, sums + i * 1024,
                                    gamma + i * 512, beta + i * 512,
                                    noise + (long)i * B_ROWS * WIDTH,
                                    Wc + 512 + i * 512,
                                    lastbf + 512 + (long)i * 512, logit);
    woff += (long)512 * K;
  }
  finalize<<<32, 256, 0, stream>>>(logit, bc, (float*)d_out);
}

// Round 4
// 287.942 us; speedup vs baseline: 1.7068x; 1.0786x over previous
//
#include <hip/hip_runtime.h>

#define B_ROWS 8192
#define WIDTH  512
#define DEPTH  7
#define CIN    4096
#define EPS    1e-5f
#define SLOPE  0.01f

typedef __attribute__((ext_vector_type(8))) short short8;
typedef __attribute__((ext_vector_type(4))) short short4v;
typedef __attribute__((ext_vector_type(4))) float f32x4;
typedef __attribute__((ext_vector_type(16))) float f32x16;

// round-to-nearest-even f32 -> bf16 bits
__device__ inline short f2bf(float f) {
  unsigned u = __builtin_bit_cast(unsigned, f);
  unsigned r = (u + 0x7FFFu + ((u >> 16) & 1u)) >> 16;
  return (short)r;
}

__device__ inline void gl_lds16(const void* g, void* l) {
  __builtin_amdgcn_global_load_lds(
      (const __attribute__((address_space(1))) unsigned*)g,
      (__attribute__((address_space(3))) unsigned*)l, 16, 0, 0);
}

// ---------------- weight conversion: 7 fp32 W's -> packed bf16 ----------------
struct WP { const float* p[7]; };

__global__ __launch_bounds__(256) void convw(WP wp, short* __restrict__ out) {
  long e = ((long)blockIdx.x * 256 + threadIdx.x) * 4;  // 4 elems/thread
  int layer; long base;
  if      (e < 262144L)  { layer = 0; base = 0; }
  else if (e < 786432L)  { layer = 1; base = 262144L; }
  else if (e < 1572864L) { layer = 2; base = 786432L; }
  else if (e < 2621440L) { layer = 3; base = 1572864L; }
  else if (e < 3932160L) { layer = 4; base = 2621440L; }
  else if (e < 5505024L) { layer = 5; base = 3932160L; }
  else                   { layer = 6; base = 5505024L; }
  f32x4 v = *(const f32x4*)(wp.p[layer] + (e - base));
  short4v o;
  o.x = f2bf(v.x); o.y = f2bf(v.y); o.z = f2bf(v.z); o.w = f2bf(v.w);
  *(short4v*)(out + e) = o;
}

// -------- x -> bf16 concat buffer + classifier partial (+ zero sums) ----------
__global__ __launch_bounds__(256) void initx(const float* __restrict__ x,
                                             const float* __restrict__ wc,
                                             short* __restrict__ lastbf,
                                             float* __restrict__ logit,
                                             float* __restrict__ sumsz) {
  int gid = blockIdx.x * 256 + threadIdx.x;
  if (gid < DEPTH * 1024) sumsz[gid] = 0.f;  // zero all layers' stats buffers
  int w = threadIdx.x >> 6, l = threadIdx.x & 63;
  int r = blockIdx.x * 4 + w;
  const float* xr = x + (long)r * 512 + l * 8;
  f32x4 v0 = *(const f32x4*)xr;
  f32x4 v1 = *(const f32x4*)(xr + 4);
  const float* wcr = wc + l * 8;
  float acc = 0.f;
  short8 ob;
#pragma unroll
  for (int j = 0; j < 4; ++j) { acc += v0[j] * wcr[j];     ob[j]     = f2bf(v0[j]); }
#pragma unroll
  for (int j = 0; j < 4; ++j) { acc += v1[j] * wcr[4 + j]; ob[4 + j] = f2bf(v1[j]); }
  *(short8*)&lastbf[(long)r * CIN + l * 8] = ob;
#pragma unroll
  for (int off = 32; off; off >>= 1) acc += __shfl_xor(acc, off);
  if (l == 0) logit[r] = acc;
}

// ---------------- bf16 MFMA GEMM + fused column stats -------------------------
// BM=128, BN=64, BK=64, grid (64,8) = 512 blocks -> 2 blocks/CU.
// 256 threads = 4 waves; wave ks in {0..3} owns K-quarter (k16 slice of each
// BK=64 tile) and covers the FULL 128x64 output tile with 32x32x16 MFMA:
// acc[4][2] f32x16, wave-tile 128x64 -> 0.75KB LDS read per 32.8 kFLOP.
// LDS: dbuf x (As 16KB + Bs 8KB) = 48KB, XOR-swizzled (byte ^ ((row&7)<<4)).
// Epilogue: ks=3/2/1 sequentially add partials into Red (aliases staging LDS),
// ks=0 combines, writes C, and atomically accumulates column sum/sumsq.
__global__ __launch_bounds__(256, 2) void gemm_fused(const short* __restrict__ A,
                                                     const short* __restrict__ Bw,
                                                     float* __restrict__ C,
                                                     float* __restrict__ sums,
                                                     int K) {
  __shared__ __align__(16) char smem[49152];  // 2 x (As 16KB + Bs 8KB)
  int t = threadIdx.x;
  int ks = t >> 6, l = t & 63;
  int l31 = l & 31, hi = l >> 5;
  int bm = blockIdx.x, bn = blockIdx.y;
  const short* Ab = A + (long)(bm * 128) * CIN;
  const short* Bb = Bw + (long)(bn * 64) * K;

  f32x16 acc[4][2];
#pragma unroll
  for (int m = 0; m < 4; ++m)
#pragma unroll
    for (int n = 0; n < 2; ++n)
#pragma unroll
      for (int r = 0; r < 16; ++r) acc[m][n][r] = 0.f;

  // staging: 24 x 1KB chunks (A: 16, B: 8); wave ks stages A chunks 4ks..4ks+3
  // and B chunks 2ks..2ks+1. dest row = chunk*8 + (l>>3); source col
  // pre-swizzled so read-side byte^((row&7)<<4) is the matching involution.
  int l8 = l >> 3;
  int scol = ((l & 7) ^ l8) << 3;  // element offset of this lane's 16B chunk

#define STAGE(buf, k0)                                                                       \
  {                                                                                          \
    char* base = smem + (buf) * 24576;                                                       \
    int c0 = ks * 4, c1 = ks * 2;                                                            \
    gl_lds16(Ab + (long)((c0    ) * 8 + l8) * CIN + (k0) + scol, base + (c0    ) * 1024);    \
    gl_lds16(Ab + (long)((c0 + 1) * 8 + l8) * CIN + (k0) + scol, base + (c0 + 1) * 1024);    \
    gl_lds16(Ab + (long)((c0 + 2) * 8 + l8) * CIN + (k0) + scol, base + (c0 + 2) * 1024);    \
    gl_lds16(Ab + (long)((c0 + 3) * 8 + l8) * CIN + (k0) + scol, base + (c0 + 3) * 1024);    \
    gl_lds16(Bb + (long)((c1    ) * 8 + l8) * K + (k0) + scol, base + 16384 + (c1    ) * 1024); \
    gl_lds16(Bb + (long)((c1 + 1) * 8 + l8) * K + (k0) + scol, base + 16384 + (c1 + 1) * 1024); \
  }

  STAGE(0, 0);
  __syncthreads();

  // fragment read offsets: wave ks reads k-bytes [ks*32, ks*32+32) of each
  // 128B row; lane's 16B at kb = ks*32 + hi*16, XOR'd with ((row&7)<<4).
  int kb = ks * 32 + hi * 16;
  int sw = (l & 7) << 4;  // row&7 == l&7 since frag rows are m*32 + l31

  int nt = K >> 6;
  int cur = 0;
  for (int tix = 0; tix < nt; ++tix) {
    if (tix + 1 < nt) STAGE(cur ^ 1, (tix + 1) << 6);
    const char* AsC = smem + cur * 24576;
    const char* BsC = AsC + 16384;
    short8 a[4], b[2];
#pragma unroll
    for (int m = 0; m < 4; ++m)
      a[m] = *(const short8*)(AsC + (m * 32 + l31) * 128 + (kb ^ sw));
#pragma unroll
    for (int n = 0; n < 2; ++n)
      b[n] = *(const short8*)(BsC + (n * 32 + l31) * 128 + (kb ^ sw));
#pragma unroll
    for (int m = 0; m < 4; ++m)
#pragma unroll
      for (int n = 0; n < 2; ++n)
        acc[m][n] = __builtin_amdgcn_mfma_f32_32x32x16_bf16(a[m], b[n], acc[m][n], 0, 0, 0);
    __syncthreads();  // staged buf^1 complete + all reads of cur done
    cur ^= 1;
  }

  // ---- combine 4 K-quarters (Red aliases staging LDS), write C, stats ----
  float* Red = (float*)smem;  // 128x64 f32 = 32KB
#define RIDX(m, n, r) (((m) * 32 + ((r) & 3) + 8 * ((r) >> 2) + 4 * hi) * 64 + (n) * 32 + l31)
  if (ks == 3) {
#pragma unroll
    for (int m = 0; m < 4; ++m)
#pragma unroll
      for (int n = 0; n < 2; ++n)
#pragma unroll
        for (int r = 0; r < 16; ++r) Red[RIDX(m, n, r)] = acc[m][n][r];
  }
  __syncthreads();
  if (ks == 2) {
#pragma unroll
    for (int m = 0; m < 4; ++m)
#pragma unroll
      for (int n = 0; n < 2; ++n)
#pragma unroll
        for (int r = 0; r < 16; ++r) Red[RIDX(m, n, r)] += acc[m][n][r];
  }
  __syncthreads();
  if (ks == 1) {
#pragma unroll
    for (int m = 0; m < 4; ++m)
#pragma unroll
      for (int n = 0; n < 2; ++n)
#pragma unroll
        for (int r = 0; r < 16; ++r) Red[RIDX(m, n, r)] += acc[m][n][r];
  }
  __syncthreads();
  if (ks == 0) {
    float* Cb = C + (long)(bm * 128) * WIDTH + bn * 64;
#pragma unroll
    for (int n = 0; n < 2; ++n) {
      float s = 0.f, q = 0.f;
#pragma unroll
      for (int m = 0; m < 4; ++m) {
#pragma unroll
        for (int r = 0; r < 16; ++r) {
          int cr = (r & 3) + 8 * (r >> 2) + 4 * hi;
          float v = acc[m][n][r] + Red[RIDX(m, n, r)];
          Cb[(long)(m * 32 + cr) * WIDTH + n * 32 + l31] = v;
          s += v; q += v * v;
        }
      }
      s += __shfl_xor(s, 32);
      q += __shfl_xor(q, 32);
      if (l < 32) {
        int colg = bn * 64 + n * 32 + l;
        atomicAdd(&sums[colg], s);
        atomicAdd(&sums[WIDTH + colg], q);
      }
    }
  }
#undef RIDX
#undef STAGE
}

// ---------------- BN + LeakyReLU + noise + classifier partial + bf16 store ----
__global__ __launch_bounds__(256) void bnact(const float* __restrict__ h,
                                             const float* __restrict__ sums,
                                             const float* __restrict__ gamma,
                                             const float* __restrict__ beta,
                                             const float* __restrict__ noise,
                                             const float* __restrict__ wc,
                                             short* __restrict__ lastseg,
                                             float* __restrict__ logit) {
  int w = threadIdx.x >> 6, l = threadIdx.x & 63;
  int r = blockIdx.x * 4 + w;
  int c = l * 8;
  const float invB = 1.0f / 8192.0f;
  f32x4 h0 = *(const f32x4*)&h[(long)r * WIDTH + c];
  f32x4 h1 = *(const f32x4*)&h[(long)r * WIDTH + c + 4];
  f32x4 n0 = *(const f32x4*)&noise[(long)r * WIDTH + c];
  f32x4 n1 = *(const f32x4*)&noise[(long)r * WIDTH + c + 4];
  float acc = 0.f;
  short8 ob;
#pragma unroll
  for (int j = 0; j < 8; ++j) {
    int cc = c + j;
    float hv = j < 4 ? h0[j] : h1[j - 4];
    float nv = j < 4 ? n0[j] : n1[j - 4];
    float mean = sums[cc] * invB;
    float var = sums[WIDTH + cc] * invB - mean * mean;
    float v = (hv - mean) * rsqrtf(var + EPS);
    v = v * gamma[cc] + beta[cc];
    v = v >= 0.f ? v : SLOPE * v;
    v *= nv;
    acc += v * wc[cc];
    ob[j] = f2bf(v);
  }
  *(short8*)&lastseg[(long)r * CIN + c] = ob;
#pragma unroll
  for (int off = 32; off; off >>= 1) acc += __shfl_xor(acc, off);
  if (l == 0) logit[r] += acc;  // one wave per row: no race
}

// ---------------- sigmoid ----------------------------------------------------
__global__ __launch_bounds__(256) void finalize(const float* __restrict__ logit,
                                                const float* __restrict__ bc,
                                                float* __restrict__ out) {
  int i = blockIdx.x * 256 + threadIdx.x;
  float z = logit[i] + bc[0];
  out[i] = 1.0f / (1.0f + expf(-z));
}

extern "C" void kernel_launch(void* const* d_in, const int* in_sizes, int n_in,
                              void* d_out, int out_size, void* d_ws, size_t ws_size,
                              hipStream_t stream) {
  (void)in_sizes; (void)n_in; (void)out_size; (void)ws_size;
  const float* x     = (const float*)d_in[0];
  WP wp;
  for (int i = 0; i < 7; ++i) wp.p[i] = (const float*)d_in[1 + i];
  // d_in[8] = b (linear bias) — cancels exactly through training-mode BN; unused.
  const float* gamma = (const float*)d_in[9];
  const float* beta  = (const float*)d_in[10];
  const float* Wc    = (const float*)d_in[11];
  const float* bc    = (const float*)d_in[12];
  const float* noise = (const float*)d_in[13];

  char* ws = (char*)d_ws;
  short* lastbf = (short*)ws;                               // 8192*4096 bf16 = 64 MiB
  float* hpre   = (float*)(ws + 67108864);                  // 8192*512 f32  = 16 MiB
  short* wbf    = (short*)(ws + 67108864 + 16777216);       // 7.34M bf16    = 14 MiB
  float* sums   = (float*)(ws + 67108864 + 16777216 + 14680064);   // 7*1024 f32
  float* logit  = (float*)(ws + 67108864 + 16777216 + 14680064 + 28672);  // 8192 f32

  convw<<<7168, 256, 0, stream>>>(wp, wbf);
  initx<<<2048, 256, 0, stream>>>(x, Wc, lastbf, logit, sums);

  long woff = 0;
  for (int i = 0; i < DEPTH; ++i) {
    int K = 512 * (i + 1);
    gemm_fused<<<dim3(64, 8), 256, 0, stream>>>(lastbf, wbf + woff, hpre,
                                                sums + i * 1024, K);
    bnact<<<2048, 256, 0, stream>>>(hpre, sums + i * 1024,
                                    gamma + i * 512, beta + i * 512,
                                    noise + (long)i * B_ROWS * WIDTH,
                                    Wc + 512 + i * 512,
                                    lastbf + 512 + (long)i * 512, logit);
    woff += (long)512 * K;
  }
  finalize<<<32, 256, 0, stream>>>(logit, bc, (float*)d_out);
}